// Round 1
// baseline (130.518 us; speedup 1.0000x reference)
//
#include <hip/hip_runtime.h>
#include <hip/hip_cooperative_groups.h>
#include <math.h>

// Problem constants (B=8, H=W=64, P=60 frequencies, N=4096 grid points)
#define NBATCH 8
#define NP 60
#define NN 4096

namespace cg = cooperative_groups;

// Fused single cooperative kernel. One block per (b, p) pair; 256 threads.
// Stage math identical to the verified two-kernel version (absmax 0.0).
// After grid.sync(), block 0 performs the final per-batch sqrt + sum.
// Cross-XCD visibility of ws partials is guaranteed with agent-scope
// release stores / acquire loads (per-XCD L2s are not coherent).
__global__ __launch_bounds__(256) void chf_fused_kernel(
    const float* __restrict__ dnn, const float* __restrict__ gt,
    float* __restrict__ ws, float* __restrict__ outp)
{
    __shared__ float Pre[256];
    __shared__ float Pim[256];
    __shared__ float Gre[64];
    __shared__ float Gim[64];
    __shared__ float sq[NBATCH];

    const int t    = threadIdx.x;
    const int blk  = blockIdx.x;
    const int b    = blk / NP;
    const int p    = blk % NP;
    const int lane = t & 63;
    const int g    = t >> 6;   // wave id 0..3

    // ---- Phase 1: G[w] = sum_h e^{i r_p y_h} * d[h][w] ----
    // lane = w (coalesced), wave g covers h in [16g, 16g+16).
    // angle(h) = 0.4*(p-30)*(2h+1); step per h: 0.8*(p-30).
    {
        const float fp = 0.4f * (float)(p - 30);
        float c, s, cs, ss;
        sincosf(fp * (float)(32 * g + 1), &s, &c);   // base at h = 16g
        sincosf(fp * 2.0f, &ss, &cs);                // per-row step
        float gr = 0.f, gi = 0.f;
        const float* ob = dnn + b * NN + g * 16 * 64 + lane;
        const float* gb = gt  + b * NN + g * 16 * 64 + lane;
        #pragma unroll
        for (int hh = 0; hh < 16; ++hh) {
            const float d = ob[hh * 64] - gb[hh * 64];
            gr = fmaf(c, d, gr);
            gi = fmaf(s, d, gi);
            const float cn = fmaf(c, cs, -(s * ss));
            const float sn = fmaf(s, cs,  (c * ss));
            c = cn; s = sn;
        }
        Pre[t] = gr;
        Pim[t] = gi;
    }
    __syncthreads();
    if (t < 64) {
        Gre[t] = Pre[t] + Pre[64 + t] + Pre[128 + t] + Pre[192 + t];
        Gim[t] = Pim[t] + Pim[64 + t] + Pim[128 + t] + Pim[192 + t];
    }
    __syncthreads();

    // ---- Phase 2: F[q] = sum_w e^{i r_q x_w} * G[w] ----
    // lane = q (its own fixed frequency), wave g covers w in [16g, 16g+16).
    {
        const float fq = 0.4f * (float)(lane - 30);
        float c, s, cs, ss;
        sincosf(fq * (float)(32 * g + 1), &s, &c);   // base at w = 16g
        sincosf(fq * 2.0f, &ss, &cs);
        float fr = 0.f, fi = 0.f;
        #pragma unroll
        for (int ww = 0; ww < 16; ++ww) {
            const int w = g * 16 + ww;
            const float xr = Gre[w];   // wave-broadcast
            const float xi = Gim[w];
            fr += c * xr - s * xi;
            fi += c * xi + s * xr;
            const float cn = fmaf(c, cs, -(s * ss));
            const float sn = fmaf(s, cs,  (c * ss));
            c = cn; s = sn;
        }
        Pre[t] = fr;
        Pim[t] = fi;
    }
    __syncthreads();

    // ---- Reduce sum_q |F[q]|^2 over wave 0, one partial per block ----
    if (t < 64) {
        const float Fr = Pre[t] + Pre[64 + t] + Pre[128 + t] + Pre[192 + t];
        const float Fi = Pim[t] + Pim[64 + t] + Pim[128 + t] + Pim[192 + t];
        float val = (t < NP) ? (Fr * Fr + Fi * Fi) : 0.f;
        #pragma unroll
        for (int off = 32; off > 0; off >>= 1)
            val += __shfl_down(val, off);
        if (t == 0)
            __hip_atomic_store(&ws[blk], val, __ATOMIC_RELEASE,
                               __HIP_MEMORY_SCOPE_AGENT);  // ws[b*60 + p]
    }

    cg::this_grid().sync();

    // ---- Final: block 0 reduces 8x60 partials, sqrt per batch, sum ----
    if (blk == 0) {
        // wave g handles batches g and g+4; lane indexes the 60 p-partials.
        float v0 = (lane < NP)
            ? __hip_atomic_load(&ws[g * NP + lane], __ATOMIC_ACQUIRE,
                                __HIP_MEMORY_SCOPE_AGENT) : 0.f;
        float v1 = (lane < NP)
            ? __hip_atomic_load(&ws[(g + 4) * NP + lane], __ATOMIC_ACQUIRE,
                                __HIP_MEMORY_SCOPE_AGENT) : 0.f;
        #pragma unroll
        for (int off = 32; off > 0; off >>= 1) {
            v0 += __shfl_down(v0, off);
            v1 += __shfl_down(v1, off);
        }
        if (lane == 0) { sq[g] = sqrtf(v0); sq[g + 4] = sqrtf(v1); }
        __syncthreads();
        if (t == 0) {
            float sum = 0.f;
            #pragma unroll
            for (int i = 0; i < NBATCH; ++i) sum += sq[i];
            outp[0] = sum * (0.1f / (float)NBATCH);  // CHF_TIK * mean over batch
        }
    }
}

extern "C" void kernel_launch(void* const* d_in, const int* in_sizes, int n_in,
                              void* d_out, int out_size, void* d_ws, size_t ws_size,
                              hipStream_t stream)
{
    const float* dnn = (const float*)d_in[0];
    const float* gt  = (const float*)d_in[1];
    float* outp = (float*)d_out;
    float* ws   = (float*)d_ws;   // needs 480 floats

    void* args[] = { (void*)&dnn, (void*)&gt, (void*)&ws, (void*)&outp };
    hipLaunchCooperativeKernel((const void*)chf_fused_kernel,
                               dim3(NBATCH * NP), dim3(256),
                               args, 0, stream);
}

// Round 2
// 71.586 us; speedup vs baseline: 1.8232x; 1.8232x over previous
//
#include <hip/hip_runtime.h>
#include <math.h>

// Problem constants (B=8, H=W=64, P=60 frequencies, N=4096 grid points)
#define NBATCH 8
#define NP 60
#define NN 4096

// ws layout: floats [0..479] per-(b,p) partials; floats [480..487] per-batch sqrt;
// at byte offset 4096: 8 per-batch arrive counters + 1 done counter (zeroed by
// a 64-byte hipMemsetAsync at the head of every launch/graph replay).
#define WS_CNT_BYTE_OFF 4096

// One block per (b, p) pair. 256 threads = 4 waves of 64.
// Stage math identical to the 57.4 us two-kernel baseline (absmax 0.0).
// Final reduction is folded in via arrive-and-continue device-scope atomics:
// no grid.sync, no spin, no dispatch-order assumption (G16-safe).
__global__ __launch_bounds__(256) void chf_fused_kernel(
    const float* __restrict__ dnn, const float* __restrict__ gt,
    float* __restrict__ ws, float* __restrict__ outp)
{
    __shared__ float Pre[256];
    __shared__ float Pim[256];
    __shared__ float Gre[64];
    __shared__ float Gim[64];
    __shared__ int flag1, flag2;

    const int t    = threadIdx.x;
    const int blk  = blockIdx.x;
    const int b    = blk / NP;
    const int p    = blk % NP;
    const int lane = t & 63;
    const int g    = t >> 6;   // wave id 0..3

    // ---- Phase 1: G[w] = sum_h e^{i r_p y_h} * d[h][w] ----
    // lane = w (coalesced), wave g covers h in [16g, 16g+16).
    // angle(h) = 0.4*(p-30)*(2h+1); step per h: 0.8*(p-30).
    {
        const float fp = 0.4f * (float)(p - 30);
        float c, s, cs, ss;
        sincosf(fp * (float)(32 * g + 1), &s, &c);   // base at h = 16g
        sincosf(fp * 2.0f, &ss, &cs);                // per-row step
        float gr = 0.f, gi = 0.f;
        const float* ob = dnn + b * NN + g * 16 * 64 + lane;
        const float* gb = gt  + b * NN + g * 16 * 64 + lane;
        #pragma unroll
        for (int hh = 0; hh < 16; ++hh) {
            const float d = ob[hh * 64] - gb[hh * 64];
            gr = fmaf(c, d, gr);
            gi = fmaf(s, d, gi);
            const float cn = fmaf(c, cs, -(s * ss));
            const float sn = fmaf(s, cs,  (c * ss));
            c = cn; s = sn;
        }
        Pre[t] = gr;
        Pim[t] = gi;
    }
    __syncthreads();
    if (t < 64) {
        Gre[t] = Pre[t] + Pre[64 + t] + Pre[128 + t] + Pre[192 + t];
        Gim[t] = Pim[t] + Pim[64 + t] + Pim[128 + t] + Pim[192 + t];
    }
    __syncthreads();

    // ---- Phase 2: F[q] = sum_w e^{i r_q x_w} * G[w] ----
    // lane = q (its own fixed frequency), wave g covers w in [16g, 16g+16).
    {
        const float fq = 0.4f * (float)(lane - 30);
        float c, s, cs, ss;
        sincosf(fq * (float)(32 * g + 1), &s, &c);   // base at w = 16g
        sincosf(fq * 2.0f, &ss, &cs);
        float fr = 0.f, fi = 0.f;
        #pragma unroll
        for (int ww = 0; ww < 16; ++ww) {
            const int w = g * 16 + ww;
            const float xr = Gre[w];   // wave-broadcast
            const float xi = Gim[w];
            fr += c * xr - s * xi;
            fi += c * xi + s * xr;
            const float cn = fmaf(c, cs, -(s * ss));
            const float sn = fmaf(s, cs,  (c * ss));
            c = cn; s = sn;
        }
        Pre[t] = fr;
        Pim[t] = fi;
    }
    __syncthreads();

    // ---- Reduce sum_q |F[q]|^2 over wave 0 -> one partial per block ----
    float val = 0.f;
    if (t < 64) {
        const float Fr = Pre[t] + Pre[64 + t] + Pre[128 + t] + Pre[192 + t];
        const float Fi = Pim[t] + Pim[64 + t] + Pim[128 + t] + Pim[192 + t];
        val = (t < NP) ? (Fr * Fr + Fi * Fi) : 0.f;
        #pragma unroll
        for (int off = 32; off > 0; off >>= 1)
            val += __shfl_down(val, off);
    }

    // ---- Arrive-and-continue final reduction (no spin, no grid.sync) ----
    unsigned* cnt  = (unsigned*)((char*)ws + WS_CNT_BYTE_OFF);  // [0..7] per batch
    unsigned* done = cnt + 8;
    float*    sq   = ws + NBATCH * NP;                           // [480..487]

    if (t == 0) {
        flag2 = 0;
        __hip_atomic_store(&ws[blk], val, __ATOMIC_RELEASE,
                           __HIP_MEMORY_SCOPE_AGENT);            // ws[b*60+p]
        const unsigned old = __hip_atomic_fetch_add(&cnt[b], 1u,
            __ATOMIC_ACQ_REL, __HIP_MEMORY_SCOPE_AGENT);
        flag1 = (old == NP - 1);                                 // 60th arrival
    }
    __syncthreads();

    if (flag1 && t < 64) {
        // Same shuffle-tree order as the old final kernel -> bit-identical.
        float v = (lane < NP)
            ? __hip_atomic_load(&ws[b * NP + lane], __ATOMIC_ACQUIRE,
                                __HIP_MEMORY_SCOPE_AGENT) : 0.f;
        #pragma unroll
        for (int off = 32; off > 0; off >>= 1)
            v += __shfl_down(v, off);
        if (t == 0) {
            __hip_atomic_store(&sq[b], sqrtf(v), __ATOMIC_RELEASE,
                               __HIP_MEMORY_SCOPE_AGENT);
            const unsigned old2 = __hip_atomic_fetch_add(done, 1u,
                __ATOMIC_ACQ_REL, __HIP_MEMORY_SCOPE_AGENT);
            flag2 = (old2 == NBATCH - 1);                        // 8th batch done
        }
    }
    __syncthreads();

    if (flag2 && t == 0) {
        float sum = 0.f;
        #pragma unroll
        for (int i = 0; i < NBATCH; ++i)
            sum += __hip_atomic_load(&sq[i], __ATOMIC_ACQUIRE,
                                     __HIP_MEMORY_SCOPE_AGENT);
        outp[0] = sum * (0.1f / (float)NBATCH);  // CHF_TIK * mean over batch
    }
}

extern "C" void kernel_launch(void* const* d_in, const int* in_sizes, int n_in,
                              void* d_out, int out_size, void* d_ws, size_t ws_size,
                              hipStream_t stream)
{
    const float* dnn = (const float*)d_in[0];
    const float* gt  = (const float*)d_in[1];
    float* outp = (float*)d_out;
    float* ws   = (float*)d_ws;

    // Zero the 9 arrival counters (8 per-batch + 1 done); graph-capture safe.
    hipMemsetAsync((char*)d_ws + WS_CNT_BYTE_OFF, 0, 64, stream);
    chf_fused_kernel<<<NBATCH * NP, 256, 0, stream>>>(dnn, gt, ws, outp);
}

// Round 3
// 58.025 us; speedup vs baseline: 2.2493x; 1.2337x over previous
//
#include <hip/hip_runtime.h>
#include <math.h>

// Problem constants (B=8, H=W=64, P=60 frequencies, N=4096 grid points)
#define NBATCH 8
#define NP 60
#define NG 64
#define NN 4096

// One block per (b, p) pair. 256 threads = 4 waves of 64.
// Twiddles cos/sin(0.4*(k-30)*(2j+1)) are generated by per-thread complex
// recurrence (2 sincosf + 15 rotations per phase) -- no LDS table, no phase-0.
//
// NOTE (session journal): fusing the two kernels was tried twice and both
// regressed: grid.sync cooperative launch = 130.5 us (480-block device-wide
// spin across 8 non-coherent XCDs); atomic arrive-and-continue = 71.6 us
// (dependent chain of agent-scope HBM atomics in the tail + extra memset
// node). Two thin graph nodes beat any single-node cross-block-sync
// formulation on gfx950. This two-kernel version measured 57.4 us; the
// iteration is dominated by a 39.7 us harness workspace-poison fill that
// already runs at ~85% of HBM peak.
__global__ __launch_bounds__(256) void chf_stage_kernel(
    const float* __restrict__ dnn, const float* __restrict__ gt,
    float* __restrict__ ws)
{
    __shared__ float Pre[256];
    __shared__ float Pim[256];
    __shared__ float Gre[64];
    __shared__ float Gim[64];

    const int t    = threadIdx.x;
    const int blk  = blockIdx.x;
    const int b    = blk / NP;
    const int p    = blk % NP;
    const int lane = t & 63;
    const int g    = t >> 6;   // wave id 0..3

    // ---- Phase 1: G[w] = sum_h e^{i r_p y_h} * d[h][w] ----
    // lane = w (coalesced), wave g covers h in [16g, 16g+16).
    // angle(h) = 0.4*(p-30)*(2h+1); step per h: 0.8*(p-30).
    {
        const float fp = 0.4f * (float)(p - 30);
        float c, s, cs, ss;
        sincosf(fp * (float)(32 * g + 1), &s, &c);   // base at h = 16g
        sincosf(fp * 2.0f, &ss, &cs);                // per-row step
        float gr = 0.f, gi = 0.f;
        const float* ob = dnn + b * NN + g * 16 * 64 + lane;
        const float* gb = gt  + b * NN + g * 16 * 64 + lane;
        #pragma unroll
        for (int hh = 0; hh < 16; ++hh) {
            const float d = ob[hh * 64] - gb[hh * 64];
            gr = fmaf(c, d, gr);
            gi = fmaf(s, d, gi);
            const float cn = fmaf(c, cs, -(s * ss));
            const float sn = fmaf(s, cs,  (c * ss));
            c = cn; s = sn;
        }
        Pre[t] = gr;
        Pim[t] = gi;
    }
    __syncthreads();
    if (t < 64) {
        Gre[t] = Pre[t] + Pre[64 + t] + Pre[128 + t] + Pre[192 + t];
        Gim[t] = Pim[t] + Pim[64 + t] + Pim[128 + t] + Pim[192 + t];
    }
    __syncthreads();

    // ---- Phase 2: F[q] = sum_w e^{i r_q x_w} * G[w] ----
    // lane = q (its own fixed frequency), wave g covers w in [16g, 16g+16).
    // angle(w) = 0.4*(lane-30)*(2w+1); step per w: 0.8*(lane-30).
    {
        const float fq = 0.4f * (float)(lane - 30);
        float c, s, cs, ss;
        sincosf(fq * (float)(32 * g + 1), &s, &c);   // base at w = 16g
        sincosf(fq * 2.0f, &ss, &cs);
        float fr = 0.f, fi = 0.f;
        #pragma unroll
        for (int ww = 0; ww < 16; ++ww) {
            const int w = g * 16 + ww;
            const float xr = Gre[w];   // wave-broadcast
            const float xi = Gim[w];
            fr += c * xr - s * xi;
            fi += c * xi + s * xr;
            const float cn = fmaf(c, cs, -(s * ss));
            const float sn = fmaf(s, cs,  (c * ss));
            c = cn; s = sn;
        }
        Pre[t] = fr;
        Pim[t] = fi;
    }
    __syncthreads();

    // ---- Reduce sum_q |F[q]|^2 over wave 0, one partial per block ----
    // Lanes 60..63 computed finite garbage (unused frequencies) -> gated out.
    if (t < 64) {
        const float Fr = Pre[t] + Pre[64 + t] + Pre[128 + t] + Pre[192 + t];
        const float Fi = Pim[t] + Pim[64 + t] + Pim[128 + t] + Pim[192 + t];
        float val = (t < NP) ? (Fr * Fr + Fi * Fi) : 0.f;
        #pragma unroll
        for (int off = 32; off > 0; off >>= 1)
            val += __shfl_down(val, off);
        if (t == 0) ws[blk] = val;  // ws[b*60 + p]
    }
}

// Single block: wave b reduces its 60 partials, sqrt, thread 0 sums & scales.
__global__ __launch_bounds__(512) void chf_final_kernel(
    const float* __restrict__ ws, float* __restrict__ outp)
{
    __shared__ float sq[NBATCH];
    const int t    = threadIdx.x;
    const int b    = t >> 6;
    const int lane = t & 63;
    float v = (lane < NP) ? ws[b * NP + lane] : 0.f;
    #pragma unroll
    for (int off = 32; off > 0; off >>= 1)
        v += __shfl_down(v, off);
    if (lane == 0) sq[b] = sqrtf(v);
    __syncthreads();
    if (t == 0) {
        float sum = 0.f;
        #pragma unroll
        for (int i = 0; i < NBATCH; ++i) sum += sq[i];
        outp[0] = sum * (0.1f / (float)NBATCH);  // CHF_TIK * mean over batch
    }
}

extern "C" void kernel_launch(void* const* d_in, const int* in_sizes, int n_in,
                              void* d_out, int out_size, void* d_ws, size_t ws_size,
                              hipStream_t stream)
{
    const float* dnn = (const float*)d_in[0];
    const float* gt  = (const float*)d_in[1];
    float* outp = (float*)d_out;
    float* ws   = (float*)d_ws;   // needs 480 floats

    chf_stage_kernel<<<NBATCH * NP, 256, 0, stream>>>(dnn, gt, ws);
    chf_final_kernel<<<1, 512, 0, stream>>>(ws, outp);
}